// Round 8
// baseline (30367.093 us; speedup 1.0000x reference)
//
#include <hip/hip_runtime.h>
#include <stdint.h>
#include <stddef.h>

#define T_STEPS 32768
#define HDIM    256
#define NTHR    1024

__device__ __forceinline__ float rcpf_(float x) {
#if defined(__has_builtin) && __has_builtin(__builtin_amdgcn_rcpf)
    return __builtin_amdgcn_rcpf(x);
#else
    return 1.0f / x;
#endif
}
// exact v_exp_f32: D = 2^S0
__device__ __forceinline__ float exp2f_(float x) {
    float r;
    asm("v_exp_f32 %0, %1" : "=v"(r) : "v"(x));
    return r;
}

// builtin (compiler-schedulable) int8 dot4
__device__ __forceinline__ int sdot4_(uint32_t a, uint32_t b, int c) {
#if defined(__has_builtin) && __has_builtin(__builtin_amdgcn_sdot4)
    return __builtin_amdgcn_sdot4((int)a, (int)b, c, false);
#else
    int d;
    asm("v_dot4_i32_i8 %0, %1, %2, %3" : "=v"(d) : "v"(a), "v"(b), "v"(c));
    return d;
#endif
}

// float DPP add via row_shr (legal on CDNA4; row_bcast15/31 are NOT)
#define DPPADD(v, CTRL) { \
    int _s = __builtin_amdgcn_update_dpp(0, __builtin_bit_cast(int, v), \
                                         CTRL, 0xf, 0xf, true); \
    v += __builtin_bit_cast(float, _s); }

// exact-int quad butterfly: all 4 lanes of each quad get the quad sum.
// Our k-quarter index q == lane&3, so this reduces across k-quarters.
#define QSUMI(v) { \
    int _t = __builtin_amdgcn_update_dpp(0, v, 0xB1, 0xf, 0xf, true); \
    v += _t; \
    _t = __builtin_amdgcn_update_dpp(0, v, 0x4E, 0xf, 0xf, true); \
    v += _t; }

// |w_hh| <= 1/16 exactly -> fixed scale: q = rint(w * 127/0.0625)
__device__ __forceinline__ uint32_t packw4_(const float4 v) {
    int a = __float2int_rn(v.x * 2032.0f);
    int b = __float2int_rn(v.y * 2032.0f);
    int c = __float2int_rn(v.z * 2032.0f);
    int d = __float2int_rn(v.w * 2032.0f);
    return (uint32_t)(a & 255) | ((uint32_t)(b & 255) << 8) |
           ((uint32_t)(c & 255) << 16) | ((uint32_t)(d & 255) << 24);
}

// 16 named weight dwords = one row x one 64-col k-quarter
#define LW16(N, PTR) \
    uint32_t N##_0  = packw4_((PTR)[0]),  N##_1  = packw4_((PTR)[1]),  \
             N##_2  = packw4_((PTR)[2]),  N##_3  = packw4_((PTR)[3]),  \
             N##_4  = packw4_((PTR)[4]),  N##_5  = packw4_((PTR)[5]),  \
             N##_6  = packw4_((PTR)[6]),  N##_7  = packw4_((PTR)[7]),  \
             N##_8  = packw4_((PTR)[8]),  N##_9  = packw4_((PTR)[9]),  \
             N##_10 = packw4_((PTR)[10]), N##_11 = packw4_((PTR)[11]), \
             N##_12 = packw4_((PTR)[12]), N##_13 = packw4_((PTR)[13]), \
             N##_14 = packw4_((PTR)[14]), N##_15 = packw4_((PTR)[15]);
#define PIN16(N) asm volatile("" : \
    "+v"(N##_0),"+v"(N##_1),"+v"(N##_2),"+v"(N##_3), \
    "+v"(N##_4),"+v"(N##_5),"+v"(N##_6),"+v"(N##_7), \
    "+v"(N##_8),"+v"(N##_9),"+v"(N##_10),"+v"(N##_11), \
    "+v"(N##_12),"+v"(N##_13),"+v"(N##_14),"+v"(N##_15));

// 3 gates x 1 h-dword; two parity variants -> 6 rotating acc chains,
// dependent-use spacing 6 instrs (~12 issue cyc).
#define D3A(WD, HV) \
    ar0 = sdot4_(Wr##WD, (HV), ar0); \
    az0 = sdot4_(Wz##WD, (HV), az0); \
    an0 = sdot4_(Wn##WD, (HV), an0);
#define D3B(WD, HV) \
    ar1 = sdot4_(Wr##WD, (HV), ar1); \
    az1 = sdot4_(Wz##WD, (HV), az1); \
    an1 = sdot4_(Wn##WD, (HV), an1);

// R24: demand-fit register layout. Cross-round fit (R17/18/23) shows every
// config executes ~1.5-2x the named VALU instrs: named demand > allocator's
// arch-VGPR target -> overflow homed in AGPRs (unified file) -> one
// v_accvgpr_read per use. R19 (use-site "v") and R20 (waves_per_eu) failed
// because the arch BUDGET, not the homes, is the knob. This round makes
// demand FIT: 1024 thr (16 waves, 4/SIMD pinned by the block itself),
// thread (j=tid>>2, q=tid&3) owns row j x k-quarter q: 48 weight dwords +
// 16 h regs + ~28 scalars ~= 92 < 128 (=512/4) -> all-arch by construction.
// FINGERPRINT: VGPR_Count ~96-112. Combine duplicated x4 lanes (lockstep,
// cheap) ; quad reduce via legal quad_perm; all R23-proven parts kept
// (exp2-domain, one barrier/event, LDS ring, builtin dots, 6 chains).
__global__ __launch_bounds__(NTHR, 4)
__attribute__((amdgpu_waves_per_eu(4, 4)))
void aether_gru_kernel(const float* __restrict__ xg,
                       const float* __restrict__ wih,
                       const float* __restrict__ whh,
                       const float* __restrict__ bih,
                       const float* __restrict__ bhh,
                       const float* __restrict__ wfc,
                       const float* __restrict__ bfc,
                       float* __restrict__ out,
                       float* __restrict__ pws_g) {
    const int tid  = threadIdx.x;
    const int lane = tid & 63;
    const int wv   = tid >> 6;              // wave 0..15
    const int q    = tid & 3;               // k-quarter (cols 64q..64q+63)
    const int j    = tid >> 2;              // row 0..255

    __shared__ float xlds[T_STEPS + 2];
    __shared__ __align__(16) signed char hbuf[2][HDIM];
    __shared__ __align__(16) float pwsL[128 * 16];   // fc ring (8 KB)
    __shared__ float idxL[128];                      // event-index ring

    // ---- stage x into LDS (coalesced float4) ----
    {
        const float4* xs4 = (const float4*)xg;
        float4* xd4 = (float4*)xlds;
        #pragma unroll 8
        for (int i = 0; i < T_STEPS / 4 / NTHR; ++i)
            xd4[tid + NTHR * i] = xs4[tid + NTHR * i];
        if (tid == 0) { xlds[T_STEPS] = 0.0f; xlds[T_STEPS + 1] = 0.0f; }
    }

    // ---- weights: 3 gates x my (row j, k-quarter q) = 48 dwords ----
    const float4* wb = (const float4*)whh;   // row stride = 64 float4
    LW16(Wr, wb + (size_t)(0 * HDIM + j) * 64 + q * 16)
    LW16(Wz, wb + (size_t)(1 * HDIM + j) * 64 + q * 16)
    LW16(Wn, wb + (size_t)(2 * HDIM + j) * 64 + q * 16)
    PIN16(Wr) PIN16(Wz) PIN16(Wn)

    // ---- per-row scalars, pre-folded into exp2 (log2) domain ----
    const float L1  = 1.4426950408889634f;         // log2(e)
    const float WSCALE = 0.0625f / 16129.0f;
    const float WSL  = WSCALE * L1;
    const float WSL2 = WSCALE * (2.0f * L1);
    const float wxr = wih[2 * j] * L1,               wdr = wih[2 * j + 1] * L1;
    const float wxz = wih[2 * (HDIM + j)] * L1,      wdz = wih[2 * (HDIM + j) + 1] * L1;
    const float wxn = wih[2 * (2*HDIM + j)] * (2.0f*L1),
                wdn = wih[2 * (2*HDIM + j) + 1] * (2.0f*L1);
    const float brc = (bih[j] + bhh[j]) * L1;
    const float bzc = (bih[HDIM + j] + bhh[HDIM + j]) * L1;
    const float bn2 = bih[2*HDIM + j] * (2.0f*L1);
    const float cn2 = bhh[2*HDIM + j] * (2.0f*L1);
    const float wf  = wfc[j];
    const float bf  = bfc[0];

    if (tid < 64) ((float*)&hbuf[0][0])[tid] = 0.0f;   // zero h0
    __syncthreads();

    // ---- sequential state (uniform across threads -> uniform branches) ----
    float hprev    = 0.0f;
    float last_val = xlds[0] + 1.24f;       // xs[0] + (2*THRESHOLD + 1.0)
    float last_t   = 0.0f;
    int   cnt      = 0;
    int   cur      = 0;

    float xc = xlds[0];
    float xn = xlds[1];

    float* recon = out;
    float* idxp  = out + T_STEPS + 1;

    // prime my k-quarter of h: 4 quads = 64 B
    const uint4* hb4 = (const uint4*)(&hbuf[0][0]);
    uint4 hq0 = hb4[(q << 2) + 0], hq1 = hb4[(q << 2) + 1];
    uint4 hq2 = hb4[(q << 2) + 2], hq3 = hb4[(q << 2) + 3];

    for (int t = 0; t < T_STEPS; ++t) {
        float xf = xlds[t + 2];                      // LDS prefetch, 2 ahead
        const float tf = (float)t;
        const bool ev = fabsf(xc - last_val) >= 0.12f;   // uniform

        if (ev) {
            const float dtv = (tf - last_t) * 0.01f;
            const float gir  = fmaf(wxr, xc, fmaf(wdr, dtv, brc));
            const float giz  = fmaf(wxz, xc, fmaf(wdz, dtv, bzc));
            const float gin2 = fmaf(wxn, xc, fmaf(wdn, dtv, bn2));

            int ar0 = 0, ar1 = 0, az0 = 0, az1 = 0, an0 = 0, an1 = 0;
            D3A(_0,  hq0.x) D3B(_1,  hq0.y) D3A(_2,  hq0.z) D3B(_3,  hq0.w)
            D3A(_4,  hq1.x) D3B(_5,  hq1.y) D3A(_6,  hq1.z) D3B(_7,  hq1.w)
            D3A(_8,  hq2.x) D3B(_9,  hq2.y) D3A(_10, hq2.z) D3B(_11, hq2.w)
            D3A(_12, hq3.x) D3B(_13, hq3.y) D3A(_14, hq3.z) D3B(_15, hq3.w)
            int sr = ar0 + ar1, sz = az0 + az1, sn = an0 + an1;
            // reduce across the 4 k-quarters (q == lane&3): exact int
            QSUMI(sr) QSUMI(sz) QSUMI(sn)

            // local gate combine (all 4 quad-lanes duplicate, bit-identical)
            const float prer = fmaf((float)sr, WSL, gir);    // log2 domain
            const float prez = fmaf((float)sz, WSL, giz);
            const float hn2  = fmaf((float)sn, WSL2, cn2);
            const float r  = rcpf_(1.0f + exp2f_(-prer));
            const float zz = rcpf_(1.0f + exp2f_(-prez));
            const float e2 = exp2f_(fmaf(r, hn2, gin2));
            const float n  = fmaf(-2.0f, rcpf_(e2 + 1.0f), 1.0f);
            const float hnew = fmaf(zz, hprev - n, n);       // n + z(hp-n)
            hprev = hnew;

            // publish my row's int8 h (one lane per quad)
            if (q == 0)
                hbuf[cur ^ 1][j] = (signed char)__float2int_rn(hnew * 127.0f);

            float pv = (q == 0) ? hnew * wf : 0.0f;
            const int   slot = cnt & 127;
            const float tfe  = tf;
            last_val = xc;
            last_t   = tf;
            cnt++;

            __syncthreads();                 // ONE barrier: hbuf published
            cur ^= 1;
            hb4 = (const uint4*)(&hbuf[cur][0]);
            // issue next event's h-reads now (hides under tail+scan;
            // 4 waves/SIMD cross-hide the remainder)
            hq0 = hb4[(q << 2) + 0]; hq1 = hb4[(q << 2) + 1];
            hq2 = hb4[(q << 2) + 2]; hq3 = hb4[(q << 2) + 3];
#if defined(__has_builtin) && __has_builtin(__builtin_amdgcn_sched_barrier)
            __builtin_amdgcn_sched_barrier(0);
#endif

            // ---- deferred fc tail (LDS ring only; NO global traffic) ----
            DPPADD(pv, 0x111)   // row_shr:1
            DPPADD(pv, 0x112)   // row_shr:2
            DPPADD(pv, 0x114)   // row_shr:4
            DPPADD(pv, 0x118)   // row_shr:8 -> lanes 15/31/47/63 = row16 sums
            {   // fold row16 pairs: lane^16 within 32-lane groups
                int _w = __builtin_amdgcn_ds_swizzle(
                             __builtin_bit_cast(int, pv), 0x401F);
                pv += __builtin_bit_cast(float, _w);
                // cross the two 32-halves: lane63 = wave sum (16 rows)
                pv += __shfl_xor(pv, 32, 64);
            }
            if (lane == 63) pwsL[(slot << 4) | wv] = pv;
            if (tid == 0) idxL[slot] = tfe;

            if (slot == 127) {               // flush ring chunk (1/128)
                __syncthreads();             // ring writes -> visible
                const int ch = (cnt >> 7) - 1;
                float4* dst = (float4*)(pws_g + ((size_t)ch << 11));
                const float4* src = (const float4*)pwsL;
                if (tid < 512) dst[tid] = src[tid];   // 512 float4 = ring
                if (tid < 128) idxp[(ch << 7) + tid] = idxL[tid];
                __syncthreads();             // protect ring reuse
            }
        }

        xc = xn; xn = xf;
    }

    __syncthreads();    // make last ring writes visible to the flush

    // ---- flush remainder ----
    {
        const int rem  = cnt & 127;
        const int done = cnt - rem;
        if (rem) {
            for (int i = tid; i < (rem << 4); i += NTHR)
                pws_g[((size_t)done << 4) + i] = pwsL[i];
            if (tid < rem) idxp[done + tid] = idxL[tid];
        }
    }
    if (tid == 0) out[T_STEPS] = (float)cnt;          // n_events
    for (int i = cnt + tid; i < T_STEPS; i += NTHR)
        idxp[i] = 32768.0f;                           // pad with T
    __syncthreads();                                  // drain flush stores

    // ---- epilogue: pred per event + piecewise-constant recon fill ----
    for (int k = tid; k < cnt; k += NTHR) {
        const float4* p4 = (const float4*)(pws_g + ((size_t)k << 4));
        float4 a = p4[0], b = p4[1], c = p4[2], d = p4[3];
        float pred = ((a.x + a.y) + (a.z + a.w)) + ((b.x + b.y) + (b.z + b.w))
                   + ((c.x + c.y) + (c.z + c.w)) + ((d.x + d.y) + (d.z + d.w)) + bf;
        const int t0 = (int)idxp[k];
        const int t1 = (k + 1 < cnt) ? (int)idxp[k + 1] : T_STEPS;
        for (int t = t0; t < t1; ++t) recon[t] = pred;
    }
}

extern "C" void kernel_launch(void* const* d_in, const int* in_sizes, int n_in,
                              void* d_out, int out_size, void* d_ws, size_t ws_size,
                              hipStream_t stream) {
    const float* x    = (const float*)d_in[0];
    const float* wih  = (const float*)d_in[1];
    const float* whh  = (const float*)d_in[2];
    const float* bih  = (const float*)d_in[3];
    const float* bhh  = (const float*)d_in[4];
    const float* wfc  = (const float*)d_in[5];
    const float* bfc  = (const float*)d_in[6];
    float* out = (float*)d_out;
    float* pws = (float*)d_ws;   // <= 2 MB (30592 events x 64 B)

    hipLaunchKernelGGL(aether_gru_kernel, dim3(1), dim3(NTHR), 0, stream,
                       x, wih, whh, bih, bhh, wfc, bfc, out, pws);
}

// Round 9
// 20149.875 us; speedup vs baseline: 1.5071x; 1.5071x over previous
//
#include <hip/hip_runtime.h>
#include <stdint.h>
#include <stddef.h>

#define T_STEPS 32768
#define HDIM    256
#define NTHR    512

__device__ __forceinline__ float rcpf_(float x) {
#if defined(__has_builtin) && __has_builtin(__builtin_amdgcn_rcpf)
    return __builtin_amdgcn_rcpf(x);
#else
    return 1.0f / x;
#endif
}
// exact v_exp_f32: D = 2^S0
__device__ __forceinline__ float exp2f_(float x) {
    float r;
    asm("v_exp_f32 %0, %1" : "=v"(r) : "v"(x));
    return r;
}

__device__ __forceinline__ int sdot4_(uint32_t a, uint32_t b, int c) {
#if defined(__has_builtin) && __has_builtin(__builtin_amdgcn_sdot4)
    return __builtin_amdgcn_sdot4((int)a, (int)b, c, false);
#else
    int d;
    asm("v_dot4_i32_i8 %0, %1, %2, %3" : "=v"(d) : "v"(a), "v"(b), "v"(c));
    return d;
#endif
}

// float DPP add via row_shr (legal on CDNA4; row_bcast15/31 are NOT).
#define DPPADD(v, CTRL) { \
    int _s = __builtin_amdgcn_update_dpp(0, __builtin_bit_cast(int, v), \
                                         CTRL, 0xf, 0xf, true); \
    v += __builtin_bit_cast(float, _s); }

// |w_hh| <= 1/16 exactly -> fixed scale: q = rint(w * 127/0.0625)
__device__ __forceinline__ uint32_t packw4_(const float4 v) {
    int a = __float2int_rn(v.x * 2032.0f);
    int b = __float2int_rn(v.y * 2032.0f);
    int c = __float2int_rn(v.z * 2032.0f);
    int d = __float2int_rn(v.w * 2032.0f);
    return (uint32_t)(a & 255) | ((uint32_t)(b & 255) << 8) |
           ((uint32_t)(c & 255) << 16) | ((uint32_t)(d & 255) << 24);
}

// 8 named scalar weight dwords (32 int8 weights) per group; 8 groups/gate.
#define LWG(pref, G, P, B) \
    uint32_t pref##G##0 = packw4_((P)[(B) + 0]), \
             pref##G##1 = packw4_((P)[(B) + 1]), \
             pref##G##2 = packw4_((P)[(B) + 2]), \
             pref##G##3 = packw4_((P)[(B) + 3]), \
             pref##G##4 = packw4_((P)[(B) + 4]), \
             pref##G##5 = packw4_((P)[(B) + 5]), \
             pref##G##6 = packw4_((P)[(B) + 6]), \
             pref##G##7 = packw4_((P)[(B) + 7]);
#define PING(pref, G) asm volatile("" : \
    "+v"(pref##G##0), "+v"(pref##G##1), "+v"(pref##G##2), "+v"(pref##G##3), \
    "+v"(pref##G##4), "+v"(pref##G##5), "+v"(pref##G##6), "+v"(pref##G##7));

// 24 sdot4, 9 rotating accumulator chains (3/gate) — the R17-champion DG.
#define DG(G, QA, QB, CA, CB) \
    ar##CA = sdot4_(r##G##0, (QA).x, ar##CA); ar##CA = sdot4_(r##G##1, (QA).y, ar##CA); \
    ar##CA = sdot4_(r##G##2, (QA).z, ar##CA); ar##CA = sdot4_(r##G##3, (QA).w, ar##CA); \
    ar##CB = sdot4_(r##G##4, (QB).x, ar##CB); ar##CB = sdot4_(r##G##5, (QB).y, ar##CB); \
    ar##CB = sdot4_(r##G##6, (QB).z, ar##CB); ar##CB = sdot4_(r##G##7, (QB).w, ar##CB); \
    az##CA = sdot4_(z##G##0, (QA).x, az##CA); az##CA = sdot4_(z##G##1, (QA).y, az##CA); \
    az##CA = sdot4_(z##G##2, (QA).z, az##CA); az##CA = sdot4_(z##G##3, (QA).w, az##CA); \
    az##CB = sdot4_(z##G##4, (QB).x, az##CB); az##CB = sdot4_(z##G##5, (QB).y, az##CB); \
    az##CB = sdot4_(z##G##6, (QB).z, az##CB); az##CB = sdot4_(z##G##7, (QB).w, az##CB); \
    an##CA = sdot4_(n##G##0, (QA).x, an##CA); an##CA = sdot4_(n##G##1, (QA).y, an##CA); \
    an##CA = sdot4_(n##G##2, (QA).z, an##CA); an##CA = sdot4_(n##G##3, (QA).w, an##CA); \
    an##CB = sdot4_(n##G##4, (QB).x, an##CB); an##CB = sdot4_(n##G##5, (QB).y, an##CB); \
    an##CB = sdot4_(n##G##6, (QB).z, an##CB); an##CB = sdot4_(n##G##7, (QB).w, an##CB);

// R25 = R17 champion + helper wave-set, driven by the 4-cyc/instr law
// (busy ≈ 4.1x static wave-instrs across R17/R23/R24; more waves of
// duplicated work = monotonically worse). 512 threads:
//  waves 0-3 (MAIN): exactly R17's full-row 192-dot engine + exp2-domain
//    combine (proven absmax-identical in R23/R24); fc tail/ring/flush
//    REMOVED from this critical path (~80 cyc); publishes f32 h to LDS.
//  waves 4-7 (HELPER): after the same single per-event barrier: read f32 h,
//    DPP fc-reduce, LDS ring store, and the 1/256 chunk flush (moved to
//    slot==0 of the NEXT chunk so the event barrier itself provides the
//    ring-reuse sync — R17's two per-flush barriers deleted; flush global
//    stores drain ~1700cyc before the next barrier's vmcnt(0)).
// Helper instrs fill main's idle issue slots (a lone wave uses <=1/4 of
// SIMD issue bandwidth under the 4-cyc cadence).
__global__ __launch_bounds__(NTHR)
void aether_gru_kernel(const float* __restrict__ xg,
                       const float* __restrict__ wih,
                       const float* __restrict__ whh,
                       const float* __restrict__ bih,
                       const float* __restrict__ bhh,
                       const float* __restrict__ wfc,
                       const float* __restrict__ bfc,
                       float* __restrict__ out,
                       float* __restrict__ pws_g) {
    const int tid  = threadIdx.x;
    const bool MAIN = (tid < 256);          // waves 0-3; waves 4-7 helpers
    const int ri   = tid & 255;             // row 0..255 (both roles)

    __shared__ float xlds[T_STEPS + 2];
    __shared__ __align__(16) signed char hbuf[2][HDIM];
    __shared__ __align__(16) float hf32L[256];       // f32 h for fc (exact)
    __shared__ __align__(16) float pwsL[256 * 16];   // fc partial ring (16 KB)
    __shared__ float idxL[256];                      // event-index ring

    // ---- stage x into LDS (coalesced float4) ----
    {
        const float4* xs4 = (const float4*)xg;
        float4* xd4 = (float4*)xlds;
        #pragma unroll 4
        for (int i = 0; i < T_STEPS / 4 / NTHR; ++i)
            xd4[tid + NTHR * i] = xs4[tid + NTHR * i];
        if (tid == 0) { xlds[T_STEPS] = 0.0f; xlds[T_STEPS + 1] = 0.0f; }
    }

    // ---- weights: 3 gates x 64 dwords for row ri (helpers load too —
    // in-bounds, one-time; allocation is per-kernel uniform anyway) ----
    const float4* pr = (const float4*)(whh + (size_t)ri * HDIM);
    const float4* pz = (const float4*)(whh + (size_t)(HDIM + ri) * HDIM);
    const float4* pn = (const float4*)(whh + (size_t)(2 * HDIM + ri) * HDIM);
    LWG(r,A,pr,0)  LWG(r,B,pr,8)  LWG(r,C,pr,16) LWG(r,D,pr,24)
    LWG(r,E,pr,32) LWG(r,F,pr,40) LWG(r,G,pr,48) LWG(r,H,pr,56)
    LWG(z,A,pz,0)  LWG(z,B,pz,8)  LWG(z,C,pz,16) LWG(z,D,pz,24)
    LWG(z,E,pz,32) LWG(z,F,pz,40) LWG(z,G,pz,48) LWG(z,H,pz,56)
    LWG(n,A,pn,0)  LWG(n,B,pn,8)  LWG(n,C,pn,16) LWG(n,D,pn,24)
    LWG(n,E,pn,32) LWG(n,F,pn,40) LWG(n,G,pn,48) LWG(n,H,pn,56)
    PING(r,A) PING(r,B) PING(r,C) PING(r,D)
    PING(r,E) PING(r,F) PING(r,G) PING(r,H)
    PING(z,A) PING(z,B) PING(z,C) PING(z,D)
    PING(z,E) PING(z,F) PING(z,G) PING(z,H)
    PING(n,A) PING(n,B) PING(n,C) PING(n,D)
    PING(n,E) PING(n,F) PING(n,G) PING(n,H)

    // ---- per-row scalars, exp2 (log2) domain ----
    const float L1  = 1.4426950408889634f;           // log2(e)
    const float WSCALE = 0.0625f / 16129.0f;
    const float WSL  = WSCALE * L1;
    const float WSL2 = WSCALE * (2.0f * L1);
    const float wxr = wih[2 * ri] * L1,              wdr = wih[2 * ri + 1] * L1;
    const float wxz = wih[2 * (HDIM + ri)] * L1,     wdz = wih[2 * (HDIM + ri) + 1] * L1;
    const float wxn = wih[2 * (2*HDIM + ri)] * (2.0f*L1),
                wdn = wih[2 * (2*HDIM + ri) + 1] * (2.0f*L1);
    const float brc = (bih[ri] + bhh[ri]) * L1;
    const float bzc = (bih[HDIM + ri] + bhh[HDIM + ri]) * L1;
    const float bn2 = bih[2*HDIM + ri] * (2.0f*L1);
    const float cn2 = bhh[2*HDIM + ri] * (2.0f*L1);
    const float wf  = wfc[ri];                       // helpers use
    const float bf  = bfc[0];

    if (tid < 64) ((float*)&hbuf[0][0])[tid] = 0.0f;   // zero h0
    __syncthreads();

    // ---- sequential state (uniform across threads -> uniform branches) ----
    float hprev    = 0.0f;
    float last_val = xlds[0] + 1.24f;       // xs[0] + (2*THRESHOLD + 1.0)
    float last_t   = 0.0f;
    int   cnt      = 0;
    int   cur      = 0;

    float xc = xlds[0];
    float xn = xlds[1];

    float* recon = out;
    float* idxp  = out + T_STEPS + 1;

    // prime 2-deep rolling window (4 quads)
    const uint4* hb = (const uint4*)(&hbuf[0][0]);
    uint4 qa0 = hb[0], qb0 = hb[1];
    uint4 qa1 = hb[2], qb1 = hb[3];

    for (int t = 0; t < T_STEPS; ++t) {
        float xf = xlds[t + 2];                      // LDS prefetch, 2 ahead
        const float tf = (float)t;
        const bool ev = fabsf(xc - last_val) >= 0.12f;   // uniform

        if (ev) {
            const int e    = cnt;            // this event's index
            const int slot = e & 255;

            if (MAIN) {
                const float dtv  = (tf - last_t) * 0.01f;
                const float gir  = fmaf(wxr, xc, fmaf(wdr, dtv, brc));
                const float giz  = fmaf(wxz, xc, fmaf(wdz, dtv, bzc));
                const float gin2 = fmaf(wxn, xc, fmaf(wdn, dtv, bn2));

                int ar0 = 0, ar1 = 0, ar2 = 0;
                int az0 = 0, az1 = 0, az2 = 0;
                int an0 = 0, an1 = 0, an2 = 0;
                DG(A, qa0, qb0, 0, 1)  qa0 = hb[4];  qb0 = hb[5];
                DG(B, qa1, qb1, 2, 0)  qa1 = hb[6];  qb1 = hb[7];
                DG(C, qa0, qb0, 1, 2)  qa0 = hb[8];  qb0 = hb[9];
                DG(D, qa1, qb1, 0, 1)  qa1 = hb[10]; qb1 = hb[11];
                DG(E, qa0, qb0, 2, 0)  qa0 = hb[12]; qb0 = hb[13];
                DG(F, qa1, qb1, 1, 2)  qa1 = hb[14]; qb1 = hb[15];
                DG(G, qa0, qb0, 0, 1)
                DG(H, qa1, qb1, 2, 0)
                const int ar = (ar0 + ar1) + ar2;
                const int az = (az0 + az1) + az2;
                const int an = (an0 + an1) + an2;

                const float prer = fmaf((float)ar, WSL, gir);   // log2 dom
                const float prez = fmaf((float)az, WSL, giz);
                const float hn2  = fmaf((float)an, WSL2, cn2);
                const float r  = rcpf_(1.0f + exp2f_(-prer));
                const float zz = rcpf_(1.0f + exp2f_(-prez));
                const float e2 = exp2f_(fmaf(r, hn2, gin2));
                const float n  = fmaf(-2.0f, rcpf_(e2 + 1.0f), 1.0f);
                const float hnew = fmaf(zz, hprev - n, n);      // n + z(hp-n)
                hprev = hnew;

                // publish int8 h (dots) + f32 h (fc, exact)
                hbuf[cur ^ 1][ri] = (signed char)__float2int_rn(hnew * 127.0f);
                hf32L[ri] = hnew;
            }

            last_val = xc;
            last_t   = tf;
            cnt++;

            __syncthreads();                 // ONE barrier: h published
            cur ^= 1;

            if (MAIN) {
                hb = (const uint4*)(&hbuf[cur][0]);
                // issue next event's first quads now
                qa0 = hb[0]; qb0 = hb[1];
                qa1 = hb[2]; qb1 = hb[3];
#if defined(__has_builtin) && __has_builtin(__builtin_amdgcn_sched_barrier)
                __builtin_amdgcn_sched_barrier(0);
#endif
            } else {
                // ---- helper tail: flush (before overwriting slot 0) ----
                if (slot == 0 && e > 0) {
                    const int ch = (e >> 8) - 1;     // chunk of prev 256 evts
                    float4* dst = (float4*)(pws_g + ((size_t)ch << 12));
                    const float4* src = (const float4*)pwsL;
                    // 1024 float4 over 256 helper threads = 4 each
                    dst[ri]       = src[ri];
                    dst[ri + 256] = src[ri + 256];
                    dst[ri + 512] = src[ri + 512];
                    dst[ri + 768] = src[ri + 768];
                    idxp[(ch << 8) + ri] = idxL[ri];
                }
                // ---- fc partial: f32 h * wf, DPP row16 reduce ----
                float pv = hf32L[ri] * wf;
                DPPADD(pv, 0x111)   // row_shr:1
                DPPADD(pv, 0x112)   // row_shr:2
                DPPADD(pv, 0x114)   // row_shr:4
                DPPADD(pv, 0x118)   // row_shr:8 -> lane15 of row16 = sum
                if ((tid & 15) == 15) pwsL[(slot << 4) | (ri >> 4)] = pv;
                if (ri == 0) idxL[slot] = tf;
            }
        }

        xc = xn; xn = xf;
    }

    __syncthreads();    // make last ring writes visible to the final flush

    // ---- final flush: events [fl*256, cnt) still in the ring ----
    {
        const int fl  = (cnt > 0) ? ((cnt - 1) >> 8) : 0;  // chunks flushed
        const int rem = cnt - (fl << 8);
        if (rem > 0) {
            for (int i = tid; i < (rem << 4); i += NTHR)
                pws_g[(((size_t)fl << 8) << 4) + i] = pwsL[i];
            if (tid < rem) idxp[(fl << 8) + tid] = idxL[tid];
        }
    }
    if (tid == 0) out[T_STEPS] = (float)cnt;          // n_events
    for (int i = cnt + tid; i < T_STEPS; i += NTHR)
        idxp[i] = 32768.0f;                           // pad with T
    __syncthreads();                                  // drain flush stores

    // ---- epilogue: pred per event + piecewise-constant recon fill ----
    for (int k = tid; k < cnt; k += NTHR) {
        const float4* s = (const float4*)(pws_g + ((size_t)k << 4));
        float4 a = s[0], b = s[1], c = s[2], d = s[3];
        float pred = ((a.x + a.y) + (a.z + a.w)) + ((b.x + b.y) + (b.z + b.w))
                   + ((c.x + c.y) + (c.z + c.w)) + ((d.x + d.y) + (d.z + d.w)) + bf;
        const int t0 = (int)idxp[k];
        const int t1 = (k + 1 < cnt) ? (int)idxp[k + 1] : T_STEPS;
        for (int t = t0; t < t1; ++t) recon[t] = pred;
    }
}

extern "C" void kernel_launch(void* const* d_in, const int* in_sizes, int n_in,
                              void* d_out, int out_size, void* d_ws, size_t ws_size,
                              hipStream_t stream) {
    const float* x    = (const float*)d_in[0];
    const float* wih  = (const float*)d_in[1];
    const float* whh  = (const float*)d_in[2];
    const float* bih  = (const float*)d_in[3];
    const float* bhh  = (const float*)d_in[4];
    const float* wfc  = (const float*)d_in[5];
    const float* bfc  = (const float*)d_in[6];
    float* out = (float*)d_out;
    float* pws = (float*)d_ws;   // <= 2 MB (30592 events x 64 B)

    hipLaunchKernelGGL(aether_gru_kernel, dim3(1), dim3(NTHR), 0, stream,
                       x, wih, whh, bih, bhh, wfc, bfc, out, pws);
}

// Round 10
// 19025.429 us; speedup vs baseline: 1.5961x; 1.0591x over previous
//
#include <hip/hip_runtime.h>
#include <stdint.h>
#include <stddef.h>

#define T_STEPS 32768
#define HDIM    256
#define NTHR    256

typedef int v4i __attribute__((ext_vector_type(4)));

__device__ __forceinline__ float rcpf_(float x) {
#if defined(__has_builtin) && __has_builtin(__builtin_amdgcn_rcpf)
    return __builtin_amdgcn_rcpf(x);
#else
    return 1.0f / x;
#endif
}
// exact v_exp_f32: D = 2^S0
__device__ __forceinline__ float exp2f_(float x) {
    float r;
    asm("v_exp_f32 %0, %1" : "=v"(r) : "v"(x));
    return r;
}

// i8 MFMA 16x16x64: one wave-instr = 16 outputs x 64 k (exact i32 accum).
__device__ __forceinline__ v4i mfma8_(v4i a, v4i b, v4i c) {
#if defined(__has_builtin) && __has_builtin(__builtin_amdgcn_mfma_i32_16x16x64_i8)
    return __builtin_amdgcn_mfma_i32_16x16x64_i8(a, b, c, 0, 0, 0);
#else
    v4i d;
    asm("v_mfma_i32_16x16x64_i8 %0, %1, %2, %3"
        : "=a"(d) : "v"(a), "v"(b), "a"(c));
    return d;
#endif
}

// float DPP add via row_shr (legal on CDNA4; row_bcast15/31 are NOT).
#define DPPADD(v, CTRL) { \
    int _s = __builtin_amdgcn_update_dpp(0, __builtin_bit_cast(int, v), \
                                         CTRL, 0xf, 0xf, true); \
    v += __builtin_bit_cast(float, _s); }

// |w_hh| <= 1/16 exactly -> fixed scale: q = rint(w * 127/0.0625)
__device__ __forceinline__ uint32_t packw4_(const float4 v) {
    int a = __float2int_rn(v.x * 2032.0f);
    int b = __float2int_rn(v.y * 2032.0f);
    int c = __float2int_rn(v.z * 2032.0f);
    int d = __float2int_rn(v.w * 2032.0f);
    return (uint32_t)(a & 255) | ((uint32_t)(b & 255) << 8) |
           ((uint32_t)(c & 255) << 16) | ((uint32_t)(d & 255) << 24);
}

// R26: matvec moved to the MFMA pipe. R25 validated the 4-cyc/wave-instr
// issue law -> 192 sdot4/SIMD alone ~790 cyc/event (half the event time).
// v_mfma_i32_16x16x64_i8 packs 16 outputs x 64 k per wave-instr: 48 mfma
// per wave (~245 cyc on the matrix pipe) replace the 192 sdot4.
// Layout (no redistribution, no extra barrier):
//   wave w owns rows 64w..64w+63 for ALL 3 gates = 12 chains of 16 rows,
//   4 k-tiles (K=64 each). A = h broadcast to all 16 rows (rows of D
//   redundant); B chain (g,c,kt): lane l holds W_g[64w+16c+(l&15)]
//   [64kt+(l>>4)*16 + j]. D col = lane&15 (HW-verified, dtype-independent)
//   => lane l's own acc regs hold row 64w+l's preact at chain l>>4:
//   3-instr cndmask tree per gate, zero LDS, zero extra barrier.
//   k-layout risk cancels: A and B use the SAME (lane,reg,byte)->k
//   convention, so any consistent bijection yields the correct dot.
// Helpers dropped (register budget: 192 B-frags + ~50 live arch + 48 AGPR
// acc; 1 wave/SIMD); fc back on main via R17's proven DPP+ring tail.
// Combine math identical to R25 -> absmax must stay exactly 0.0009765625
// (built-in layout-correctness fingerprint).
__global__ __launch_bounds__(NTHR)
void aether_gru_kernel(const float* __restrict__ xg,
                       const float* __restrict__ wih,
                       const float* __restrict__ whh,
                       const float* __restrict__ bih,
                       const float* __restrict__ bhh,
                       const float* __restrict__ wfc,
                       const float* __restrict__ bfc,
                       float* __restrict__ out,
                       float* __restrict__ pws_g) {
    const int tid  = threadIdx.x;
    const int lane = tid & 63;
    const int ri   = tid;                   // combine row 0..255 (= 64*wv+lane)
    const int rbase = (tid >> 6) << 6;      // wave row base 64w
    const int col  = lane & 15;             // chain col
    const int loff = (lane >> 4) << 4;      // k sub-offset within a k-tile

    __shared__ float xlds[T_STEPS + 2];
    __shared__ __align__(16) signed char hbuf[2][HDIM];
    __shared__ __align__(16) float pwsL[256 * 16];   // fc partial ring (16 KB)
    __shared__ float idxL[256];                      // event-index ring

    // ---- stage x into LDS (coalesced float4) ----
    {
        const float4* xs4 = (const float4*)xg;
        float4* xd4 = (float4*)xlds;
        #pragma unroll 4
        for (int i = 0; i < T_STEPS / 4 / NTHR; ++i)
            xd4[tid + NTHR * i] = xs4[tid + NTHR * i];
        if (tid == 0) { xlds[T_STEPS] = 0.0f; xlds[T_STEPS + 1] = 0.0f; }
    }

    // ---- B-fragments: 3 gates x 4 chains x 4 k-tiles = 48 v4i ----
    // chain (g,c,kt): lane l = 16 i8 of W_g row (rbase+16c+col),
    // k = 64*kt + loff .. +15  (same k convention as A below).
#define LDB(NAME, g, c, kt) \
    v4i NAME; { \
        const float4* _r4 = (const float4*)(whh + \
            ((size_t)((g) * HDIM + rbase + 16 * (c) + col)) * HDIM + \
            64 * (kt) + loff); \
        NAME = (v4i){ (int)packw4_(_r4[0]), (int)packw4_(_r4[1]), \
                      (int)packw4_(_r4[2]), (int)packw4_(_r4[3]) }; }
    LDB(Br00,0,0,0) LDB(Br01,0,0,1) LDB(Br02,0,0,2) LDB(Br03,0,0,3)
    LDB(Br10,0,1,0) LDB(Br11,0,1,1) LDB(Br12,0,1,2) LDB(Br13,0,1,3)
    LDB(Br20,0,2,0) LDB(Br21,0,2,1) LDB(Br22,0,2,2) LDB(Br23,0,2,3)
    LDB(Br30,0,3,0) LDB(Br31,0,3,1) LDB(Br32,0,3,2) LDB(Br33,0,3,3)
    LDB(Bz00,1,0,0) LDB(Bz01,1,0,1) LDB(Bz02,1,0,2) LDB(Bz03,1,0,3)
    LDB(Bz10,1,1,0) LDB(Bz11,1,1,1) LDB(Bz12,1,1,2) LDB(Bz13,1,1,3)
    LDB(Bz20,1,2,0) LDB(Bz21,1,2,1) LDB(Bz22,1,2,2) LDB(Bz23,1,2,3)
    LDB(Bz30,1,3,0) LDB(Bz31,1,3,1) LDB(Bz32,1,3,2) LDB(Bz33,1,3,3)
    LDB(Bn00,2,0,0) LDB(Bn01,2,0,1) LDB(Bn02,2,0,2) LDB(Bn03,2,0,3)
    LDB(Bn10,2,1,0) LDB(Bn11,2,1,1) LDB(Bn12,2,1,2) LDB(Bn13,2,1,3)
    LDB(Bn20,2,2,0) LDB(Bn21,2,2,1) LDB(Bn22,2,2,2) LDB(Bn23,2,2,3)
    LDB(Bn30,2,3,0) LDB(Bn31,2,3,1) LDB(Bn32,2,3,2) LDB(Bn33,2,3,3)

    const v4i zero4 = {0, 0, 0, 0};

    // ---- per-row scalars (row = ri), exp2 (log2) domain — as R25 ----
    const float L1  = 1.4426950408889634f;           // log2(e)
    const float WSCALE = 0.0625f / 16129.0f;
    const float WSL  = WSCALE * L1;
    const float WSL2 = WSCALE * (2.0f * L1);
    const float wxr = wih[2 * ri] * L1,              wdr = wih[2 * ri + 1] * L1;
    const float wxz = wih[2 * (HDIM + ri)] * L1,     wdz = wih[2 * (HDIM + ri) + 1] * L1;
    const float wxn = wih[2 * (2*HDIM + ri)] * (2.0f*L1),
                wdn = wih[2 * (2*HDIM + ri) + 1] * (2.0f*L1);
    const float brc = (bih[ri] + bhh[ri]) * L1;
    const float bzc = (bih[HDIM + ri] + bhh[HDIM + ri]) * L1;
    const float bn2 = bih[2*HDIM + ri] * (2.0f*L1);
    const float cn2 = bhh[2*HDIM + ri] * (2.0f*L1);
    const float wf  = wfc[ri];
    const float bf  = bfc[0];

    if (tid < 64) ((float*)&hbuf[0][0])[tid] = 0.0f;   // zero h0
    __syncthreads();

    // ---- sequential state (uniform across threads -> uniform branches) ----
    float hprev    = 0.0f;
    float last_val = xlds[0] + 1.24f;       // xs[0] + (2*THRESHOLD + 1.0)
    float last_t   = 0.0f;
    int   cnt      = 0;
    int   cur      = 0;

    float xc = xlds[0];
    float xn = xlds[1];

    float* recon = out;
    float* idxp  = out + T_STEPS + 1;

    // prime A-fragments (h broadcast): lane l reads h[64*kt + loff .. +15]
    const char* hbp = (const char*)&hbuf[0][0];
    v4i A0 = *(const v4i*)(hbp +   0 + loff);
    v4i A1 = *(const v4i*)(hbp +  64 + loff);
    v4i A2 = *(const v4i*)(hbp + 128 + loff);
    v4i A3 = *(const v4i*)(hbp + 192 + loff);

    for (int t = 0; t < T_STEPS; ++t) {
        float xf = xlds[t + 2];                      // LDS prefetch, 2 ahead
        const float tf = (float)t;
        const bool ev = fabsf(xc - last_val) >= 0.12f;   // uniform

        if (ev) {
            const float dtv  = (tf - last_t) * 0.01f;
            const float gir  = fmaf(wxr, xc, fmaf(wdr, dtv, brc));
            const float giz  = fmaf(wxz, xc, fmaf(wdz, dtv, bzc));
            const float gin2 = fmaf(wxn, xc, fmaf(wdn, dtv, bn2));

            // ---- 48 mfma: 12 chains x 4 k-tiles, 12-way ILP ----
            v4i aR0 = mfma8_(A0, Br00, zero4);
            v4i aR1 = mfma8_(A0, Br10, zero4);
            v4i aR2 = mfma8_(A0, Br20, zero4);
            v4i aR3 = mfma8_(A0, Br30, zero4);
            v4i aZ0 = mfma8_(A0, Bz00, zero4);
            v4i aZ1 = mfma8_(A0, Bz10, zero4);
            v4i aZ2 = mfma8_(A0, Bz20, zero4);
            v4i aZ3 = mfma8_(A0, Bz30, zero4);
            v4i aN0 = mfma8_(A0, Bn00, zero4);
            v4i aN1 = mfma8_(A0, Bn10, zero4);
            v4i aN2 = mfma8_(A0, Bn20, zero4);
            v4i aN3 = mfma8_(A0, Bn30, zero4);

            aR0 = mfma8_(A1, Br01, aR0); aR1 = mfma8_(A1, Br11, aR1);
            aR2 = mfma8_(A1, Br21, aR2); aR3 = mfma8_(A1, Br31, aR3);
            aZ0 = mfma8_(A1, Bz01, aZ0); aZ1 = mfma8_(A1, Bz11, aZ1);
            aZ2 = mfma8_(A1, Bz21, aZ2); aZ3 = mfma8_(A1, Bz31, aZ3);
            aN0 = mfma8_(A1, Bn01, aN0); aN1 = mfma8_(A1, Bn11, aN1);
            aN2 = mfma8_(A1, Bn21, aN2); aN3 = mfma8_(A1, Bn31, aN3);

            aR0 = mfma8_(A2, Br02, aR0); aR1 = mfma8_(A2, Br12, aR1);
            aR2 = mfma8_(A2, Br22, aR2); aR3 = mfma8_(A2, Br32, aR3);
            aZ0 = mfma8_(A2, Bz02, aZ0); aZ1 = mfma8_(A2, Bz12, aZ1);
            aZ2 = mfma8_(A2, Bz22, aZ2); aZ3 = mfma8_(A2, Bz32, aZ3);
            aN0 = mfma8_(A2, Bn02, aN0); aN1 = mfma8_(A2, Bn12, aN1);
            aN2 = mfma8_(A2, Bn22, aN2); aN3 = mfma8_(A2, Bn32, aN3);

            aR0 = mfma8_(A3, Br03, aR0); aR1 = mfma8_(A3, Br13, aR1);
            aR2 = mfma8_(A3, Br23, aR2); aR3 = mfma8_(A3, Br33, aR3);
            aZ0 = mfma8_(A3, Bz03, aZ0); aZ1 = mfma8_(A3, Bz13, aZ1);
            aZ2 = mfma8_(A3, Bz23, aZ2); aZ3 = mfma8_(A3, Bz33, aZ3);
            aN0 = mfma8_(A3, Bn03, aN0); aN1 = mfma8_(A3, Bn13, aN1);
            aN2 = mfma8_(A3, Bn23, aN2); aN3 = mfma8_(A3, Bn33, aN3);

            // ---- per-lane preact select: chain = lane>>4, col = lane&15.
            // D rows are redundant (A rows broadcast) -> reg 0 valid. ----
            const bool c16 = (lane & 16) != 0;
            const bool c32 = (lane & 32) != 0;
            const int sr = c32 ? (c16 ? aR3[0] : aR2[0])
                               : (c16 ? aR1[0] : aR0[0]);
            const int sz = c32 ? (c16 ? aZ3[0] : aZ2[0])
                               : (c16 ? aZ1[0] : aZ0[0]);
            const int sn = c32 ? (c16 ? aN3[0] : aN2[0])
                               : (c16 ? aN1[0] : aN0[0]);

            // ---- combine (identical math to R25) ----
            const float prer = fmaf((float)sr, WSL, gir);
            const float prez = fmaf((float)sz, WSL, giz);
            const float hn2  = fmaf((float)sn, WSL2, cn2);
            const float r  = rcpf_(1.0f + exp2f_(-prer));
            const float zz = rcpf_(1.0f + exp2f_(-prez));
            const float e2 = exp2f_(fmaf(r, hn2, gin2));
            const float n  = fmaf(-2.0f, rcpf_(e2 + 1.0f), 1.0f);
            const float hnew = fmaf(zz, hprev - n, n);       // n + z(hp-n)
            hprev = hnew;

            // quantize + publish int8 h (row = ri = tid)
            hbuf[cur ^ 1][ri] = (signed char)__float2int_rn(hnew * 127.0f);

            float pv = hnew * wf;
            const int   slot = cnt & 255;
            const float tfe  = tf;
            last_val = xc;
            last_t   = tf;
            cnt++;

            __syncthreads();                 // ONE barrier: hbuf published
            cur ^= 1;
            {   // prefetch next event's A-fragments (4 ds_read_b128)
                const char* hb2 = (const char*)&hbuf[cur][0];
                A0 = *(const v4i*)(hb2 +   0 + loff);
                A1 = *(const v4i*)(hb2 +  64 + loff);
                A2 = *(const v4i*)(hb2 + 128 + loff);
                A3 = *(const v4i*)(hb2 + 192 + loff);
            }
#if defined(__has_builtin) && __has_builtin(__builtin_amdgcn_sched_barrier)
            __builtin_amdgcn_sched_barrier(0);   // don't sink the A loads
#endif

            // ---- deferred fc tail: DPP row16 reduce -> LDS ring ----
            DPPADD(pv, 0x111)   // row_shr:1
            DPPADD(pv, 0x112)   // row_shr:2
            DPPADD(pv, 0x114)   // row_shr:4
            DPPADD(pv, 0x118)   // row_shr:8 -> lane15 of each row16 = sum
            if ((lane & 15) == 15) pwsL[(slot << 4) | (tid >> 4)] = pv;
            if (tid == 0) idxL[slot] = tfe;

            if (slot == 255) {               // flush full ring chunk (1/256)
                __syncthreads();             // ring writes -> visible
                const int ch = (cnt >> 8) - 1;
                float4* dst = (float4*)(pws_g + ((size_t)ch << 12));
                const float4* src = (const float4*)pwsL;
                dst[tid]       = src[tid];
                dst[tid + 256] = src[tid + 256];
                dst[tid + 512] = src[tid + 512];
                dst[tid + 768] = src[tid + 768];
                idxp[(ch << 8) + tid] = idxL[tid];
                __syncthreads();             // protect ring reuse
            }
        }

        xc = xn; xn = xf;
    }

    __syncthreads();    // make last ring writes visible to the flush

    // ---- flush remainder ----
    {
        const int rem  = cnt & 255;
        const int done = cnt - rem;
        if (rem) {
            for (int i = tid; i < (rem << 4); i += NTHR)
                pws_g[((size_t)done << 4) + i] = pwsL[i];
            if (tid < rem) idxp[done + tid] = idxL[tid];
        }
    }
    if (tid == 0) out[T_STEPS] = (float)cnt;          // n_events
    for (int i = cnt + tid; i < T_STEPS; i += NTHR)
        idxp[i] = 32768.0f;                           // pad with T
    __syncthreads();                                  // drain flush stores

    // ---- epilogue: pred per event + piecewise-constant recon fill ----
    for (int k = tid; k < cnt; k += NTHR) {
        const float4* s = (const float4*)(pws_g + ((size_t)k << 4));
        float4 a = s[0], b = s[1], c = s[2], d = s[3];
        float pred = ((a.x + a.y) + (a.z + a.w)) + ((b.x + b.y) + (b.z + b.w))
                   + ((c.x + c.y) + (c.z + c.w)) + ((d.x + d.y) + (d.z + d.w)) + bf;
        const int t0 = (int)idxp[k];
        const int t1 = (k + 1 < cnt) ? (int)idxp[k + 1] : T_STEPS;
        for (int t = t0; t < t1; ++t) recon[t] = pred;
    }
}

extern "C" void kernel_launch(void* const* d_in, const int* in_sizes, int n_in,
                              void* d_out, int out_size, void* d_ws, size_t ws_size,
                              hipStream_t stream) {
    const float* x    = (const float*)d_in[0];
    const float* wih  = (const float*)d_in[1];
    const float* whh  = (const float*)d_in[2];
    const float* bih  = (const float*)d_in[3];
    const float* bhh  = (const float*)d_in[4];
    const float* wfc  = (const float*)d_in[5];
    const float* bfc  = (const float*)d_in[6];
    float* out = (float*)d_out;
    float* pws = (float*)d_ws;   // <= 2 MB (30592 events x 64 B)

    hipLaunchKernelGGL(aether_gru_kernel, dim3(1), dim3(NTHR), 0, stream,
                       x, wih, whh, bih, bhh, wfc, bfc, out, pws);
}